// Round 4
// baseline (116.228 us; speedup 1.0000x reference)
//
#include <hip/hip_runtime.h>

// 4 rows per thread: every global access is a dense float4.
__global__ __launch_bounds__(256) void bingham_kl_kernel4(
    const float4* __restrict__ q1, const float4* __restrict__ z1,
    const float4* __restrict__ q2, const float4* __restrict__ z2,
    const float4* __restrict__ F1, const float4* __restrict__ dF1,
    const float4* __restrict__ F2, float4* __restrict__ out, int nquads)
{
    int t = blockIdx.x * blockDim.x + threadIdx.x;
    if (t >= nquads) return;   // nquads = B/4

    // ---- issue all loads up front (ILP) ----
    float4 Q1[4], Q2[4];
    #pragma unroll
    for (int r = 0; r < 4; ++r) { Q1[r] = q1[4*t + r]; Q2[r] = q2[4*t + r]; }

    float4 Z1v[3], Z2v[3], G[3];
    #pragma unroll
    for (int j = 0; j < 3; ++j) { Z1v[j] = z1[3*t + j]; Z2v[j] = z2[3*t + j]; G[j] = dF1[3*t + j]; }

    const float4 f1v = F1[t];
    const float4 f2v = F2[t];

    const float* z1f = reinterpret_cast<const float*>(Z1v);
    const float* z2f = reinterpret_cast<const float*>(Z2v);
    const float* gf  = reinterpret_cast<const float*>(G);
    const float* f1f = reinterpret_cast<const float*>(&f1v);
    const float* f2f = reinterpret_cast<const float*>(&f2v);

    float4 res;
    float* resf = reinterpret_cast<float*>(&res);

    #pragma unroll
    for (int r = 0; r < 4; ++r) {
        const float a1 = Q1[r].x, b1 = Q1[r].y, c1 = Q1[r].z, d1 = Q1[r].w;
        const float a2 = Q2[r].x, b2 = Q2[r].y, c2 = Q2[r].z, d2 = Q2[r].w;

        // V2 rows (quat basis of q2)
        const float w[3][4] = {
            {  d2,  c2, -b2, -a2 },
            { -c2,  d2,  a2, -b2 },
            { -b2,  a2, -d2,  c2 }
        };
        // V1_ft = [q1 | V1^T] is orthogonal -> inverse = transpose; columns:
        const float col[4][4] = {
            {  a1,  b1,  c1,  d1 },
            {  d1,  c1, -b1, -a1 },
            { -c1,  d1,  a1, -b1 },
            { -b1,  a1, -d1,  c1 }
        };

        const float z10 = z1f[3*r+0], z11 = z1f[3*r+1], z12 = z1f[3*r+2];
        const float z20 = z2f[3*r+0], z21 = z2f[3*r+1], z22 = z2f[3*r+2];
        const float g0  = gf[3*r+0],  g1  = gf[3*r+1],  g2  = gf[3*r+2];
        const float f1  = f1f[r];
        const float f2  = f2f[r];

        const float inv_f1 = 1.0f / f1;
        const float r0 = g0 * inv_f1, r1 = g1 * inv_f1, r2 = g2 * inv_f1;
        const float s = 1.0f - (r0 + r1 + r2);

        float H[3];
        #pragma unroll
        for (int ii = 0; ii < 3; ++ii) {
            float A0 = w[ii][0]*col[0][0] + w[ii][1]*col[0][1] + w[ii][2]*col[0][2] + w[ii][3]*col[0][3];
            float A1 = w[ii][0]*col[1][0] + w[ii][1]*col[1][1] + w[ii][2]*col[1][2] + w[ii][3]*col[1][3];
            float A2 = w[ii][0]*col[2][0] + w[ii][1]*col[2][1] + w[ii][2]*col[2][2] + w[ii][3]*col[2][3];
            float A3 = w[ii][0]*col[3][0] + w[ii][1]*col[3][1] + w[ii][2]*col[3][2] + w[ii][3]*col[3][3];
            H[ii] = A0*A0*s + A1*A1*r0 + A2*A2*r1 + A3*A3*r2;
        }

        const float cross = __logf(f2) - (z22*H[0] + z21*H[1] + z20*H[2]);
        const float ent1  = __logf(f1) - (z12*g0 + z11*g1 + z10*g2) * inv_f1;
        resf[r] = cross - ent1;
    }

    out[t] = res;
}

extern "C" void kernel_launch(void* const* d_in, const int* in_sizes, int n_in,
                              void* d_out, int out_size, void* d_ws, size_t ws_size,
                              hipStream_t stream) {
    const float4* q1  = (const float4*)d_in[0];
    const float4* z1  = (const float4*)d_in[1];
    const float4* q2  = (const float4*)d_in[2];
    const float4* z2  = (const float4*)d_in[3];
    const float4* F1  = (const float4*)d_in[4];
    const float4* dF1 = (const float4*)d_in[5];
    const float4* F2  = (const float4*)d_in[6];
    float4* out = (float4*)d_out;

    const int n = out_size;        // B rows (multiple of 4: B = 2^20)
    const int nquads = n >> 2;
    const int block = 256;
    const int grid = (nquads + block - 1) / block;
    bingham_kl_kernel4<<<grid, block, 0, stream>>>(q1, z1, q2, z2, F1, dF1, F2, out, nquads);
}